// Round 1
// baseline (1845.442 us; speedup 1.0000x reference)
//
#include <hip/hip_runtime.h>
#include <math.h>

// Sinkhorn-Knopp, log domain, restructured:
//   A0[i,j] = (mean + std*eps)/TAU   (stored once in d_out, read-only after)
//   repeat 30: r_i = lse_j(A0[i,j]-c_j); c_j = lse_i(A0[i,j]-r_i)
//   out[i,j] = exp(A0[i,j]-r_i-c_j)
// No max-subtraction needed: |A0| <= ~28 -> exp fits easily in f32.

constexpr int N  = 4096;
constexpr int N4 = N / 4;      // 1024 float4 per row
constexpr float INV_TAU = 0.5f;

// ---------------------------------------------------------------- init ------
__global__ __launch_bounds__(256) void k_init(const float* __restrict__ eps,
                                              const float* __restrict__ mean,
                                              const float* __restrict__ stdv,
                                              float* __restrict__ A0,
                                              float* __restrict__ c) {
    const int idx   = blockIdx.x * blockDim.x + threadIdx.x;
    const int total = N * N / 4;
    const float4* e4 = (const float4*)eps;
    const float4* m4 = (const float4*)mean;
    const float4* s4 = (const float4*)stdv;
    float4*       a4 = (float4*)A0;
    for (int v = idx; v < total; v += gridDim.x * blockDim.x) {
        float4 e = e4[v], m = m4[v], s = s4[v];
        float4 a;
        a.x = (m.x + s.x * e.x) * INV_TAU;
        a.y = (m.y + s.y * e.y) * INV_TAU;
        a.z = (m.z + s.z * e.z) * INV_TAU;
        a.w = (m.w + s.w * e.w) * INV_TAU;
        a4[v] = a;
    }
    if (idx < N) c[idx] = 0.0f;   // c starts at zero (ws is poisoned 0xAA)
}

// ------------------------------------------------------------- row LSE ------
// One wave (64 lanes) per row: r[i] = log( sum_j exp(A0[i,j] - c[j]) )
__global__ __launch_bounds__(256) void k_row(const float* __restrict__ A0,
                                             const float* __restrict__ c,
                                             float* __restrict__ r) {
    const int wave = (blockIdx.x * blockDim.x + threadIdx.x) >> 6; // == row
    const int lane = threadIdx.x & 63;
    const float4* a4 = (const float4*)(A0 + (size_t)wave * N);
    const float4* c4 = (const float4*)c;
    float s = 0.0f;
    for (int j = lane; j < N4; j += 64) {
        float4 a  = a4[j];
        float4 cc = c4[j];
        s += __expf(a.x - cc.x) + __expf(a.y - cc.y) +
             __expf(a.z - cc.z) + __expf(a.w - cc.w);
    }
    #pragma unroll
    for (int off = 32; off > 0; off >>= 1) s += __shfl_xor(s, off, 64);
    if (lane == 0) r[wave] = __logf(s);
}

// ------------------------------------------------------------- col LSE ------
// Block = 512 threads handles a 16-column strip: c[j] = log(sum_i exp(A0-r_i))
__global__ __launch_bounds__(512) void k_col(const float* __restrict__ A0,
                                             const float* __restrict__ r,
                                             float* __restrict__ c) {
    __shared__ float lr[N];       // 16 KB: whole r vector
    __shared__ float red[512];
    const int t = threadIdx.x;
    for (int i = t; i < N; i += 512) lr[i] = r[i];
    __syncthreads();

    const int col  = blockIdx.x * 16 + (t & 15);
    const int row0 = t >> 4;                      // 0..31
    const float* __restrict__ Ac = A0 + col;
    float s = 0.0f;
    for (int row = row0; row < N; row += 32)
        s += __expf(Ac[(size_t)row * N] - lr[row]);

    red[t] = s;
    __syncthreads();
    #pragma unroll
    for (int off = 256; off >= 16; off >>= 1) {
        if (t < off) red[t] += red[t + off];
        __syncthreads();
    }
    if (t < 16) c[col] = __logf(red[t]);
}

// --------------------------------------------------------------- final ------
__global__ __launch_bounds__(256) void k_final(float* __restrict__ A0,
                                               const float* __restrict__ r,
                                               const float* __restrict__ c) {
    const int idx   = blockIdx.x * blockDim.x + threadIdx.x;
    const int total = N * N / 4;
    float4*       a4 = (float4*)A0;
    const float4* c4 = (const float4*)c;
    for (int v = idx; v < total; v += gridDim.x * blockDim.x) {
        const int row = v >> 10;          // v / (N/4)
        float4 a  = a4[v];
        float4 cc = c4[v & (N4 - 1)];
        const float ri = r[row];
        float4 o;
        o.x = __expf(a.x - ri - cc.x);
        o.y = __expf(a.y - ri - cc.y);
        o.z = __expf(a.z - ri - cc.z);
        o.w = __expf(a.w - ri - cc.w);
        a4[v] = o;
    }
}

// ------------------------------------------------------------- launcher -----
extern "C" void kernel_launch(void* const* d_in, const int* in_sizes, int n_in,
                              void* d_out, int out_size, void* d_ws, size_t ws_size,
                              hipStream_t stream) {
    const float* eps  = (const float*)d_in[0];
    const float* mean = (const float*)d_in[1];
    const float* stdv = (const float*)d_in[2];
    float* out = (float*)d_out;          // holds A0 during iterations, exp(A) at end
    float* r   = (float*)d_ws;           // N floats
    float* c   = r + N;                  // N floats

    k_init<<<4096, 256, 0, stream>>>(eps, mean, stdv, out, c);
    for (int it = 0; it < 30; ++it) {
        k_row<<<1024, 256, 0, stream>>>(out, c, r);
        k_col<<<256, 512, 0, stream>>>(out, r, c);
    }
    k_final<<<4096, 256, 0, stream>>>(out, r, c);
}

// Round 2
// 1659.138 us; speedup vs baseline: 1.1123x; 1.1123x over previous
//
#include <hip/hip_runtime.h>
#include <math.h>

// Linear-domain Sinkhorn-Knopp:
//   P = exp((mean + std*eps)/TAU)   stored ONCE (bf16 in ws if it fits, else f32 in d_out)
//   v=1; repeat 30: u_i = 1/sum_j P_ij v_j ;  v_j = 1/sum_i P_ij u_i
//   out_ij = u_i P_ij v_j
// No transcendentals in the 60 hot passes; bf16 halves traffic (32 MiB, L3-resident).

constexpr int N  = 4096;
constexpr int IT = 30;

typedef __attribute__((ext_vector_type(8))) unsigned short ushort8;

__device__ inline float bf2f(unsigned int h) {
    union { unsigned int u; float f; } x; x.u = h << 16; return x.f;
}
__device__ inline unsigned short f2bf(float f) {
    union { float f; unsigned int u; } x; x.f = f;
    unsigned int r = x.u + 0x7FFFu + ((x.u >> 16) & 1u);  // round-nearest-even
    return (unsigned short)(r >> 16);
}

struct V8 { float v[8]; };

template<typename PT>
__device__ inline V8 loadP8(const PT* base, int e);

template<> __device__ inline V8 loadP8<unsigned short>(const unsigned short* base, int e) {
    ushort8 p = *(const ushort8*)(base + e);      // one global_load_dwordx4
    V8 r;
    #pragma unroll
    for (int k = 0; k < 8; ++k) r.v[k] = bf2f((unsigned int)p[k]);
    return r;
}
template<> __device__ inline V8 loadP8<float>(const float* base, int e) {
    float4 a = *(const float4*)(base + e);
    float4 b = *(const float4*)(base + e + 4);
    V8 r = {{a.x, a.y, a.z, a.w, b.x, b.y, b.z, b.w}};
    return r;
}

// ---------------------------------------------------------------- init ------
template<typename PT>
__global__ __launch_bounds__(256) void k_init(const float* __restrict__ eps,
                                              const float* __restrict__ mean,
                                              const float* __restrict__ stdv,
                                              PT* __restrict__ P,
                                              float* __restrict__ csum,
                                              float* __restrict__ vinv,
                                              int* __restrict__ counter) {
    const int idx    = blockIdx.x * blockDim.x + threadIdx.x;
    const int total8 = N * N / 8;
    const int stride = gridDim.x * blockDim.x;
    const float4* e4 = (const float4*)eps;
    const float4* m4 = (const float4*)mean;
    const float4* s4 = (const float4*)stdv;
    for (int v = idx; v < total8; v += stride) {
        float4 e0 = e4[2 * (size_t)v], e1 = e4[2 * (size_t)v + 1];
        float4 m0 = m4[2 * (size_t)v], m1 = m4[2 * (size_t)v + 1];
        float4 s0 = s4[2 * (size_t)v], s1 = s4[2 * (size_t)v + 1];
        float p[8];
        p[0] = __expf((m0.x + s0.x * e0.x) * 0.5f);
        p[1] = __expf((m0.y + s0.y * e0.y) * 0.5f);
        p[2] = __expf((m0.z + s0.z * e0.z) * 0.5f);
        p[3] = __expf((m0.w + s0.w * e0.w) * 0.5f);
        p[4] = __expf((m1.x + s1.x * e1.x) * 0.5f);
        p[5] = __expf((m1.y + s1.y * e1.y) * 0.5f);
        p[6] = __expf((m1.z + s1.z * e1.z) * 0.5f);
        p[7] = __expf((m1.w + s1.w * e1.w) * 0.5f);
        if constexpr (sizeof(PT) == 2) {
            ushort8 o;
            #pragma unroll
            for (int k = 0; k < 8; ++k) o[k] = f2bf(p[k]);
            *(ushort8*)((unsigned short*)P + 8 * (size_t)v) = o;
        } else {
            float4 a = {p[0], p[1], p[2], p[3]}, b = {p[4], p[5], p[6], p[7]};
            float4* o4 = (float4*)P;
            o4[2 * (size_t)v]     = a;
            o4[2 * (size_t)v + 1] = b;
        }
    }
    if (idx < N) { csum[idx] = 0.0f; vinv[idx] = 1.0f; }
    if (idx == 0) *counter = 0;
}

// ------------------------------------------------------------- row pass -----
// One wave per row: rsum_i = sum_j P_ij * vinv_j.  vinv read from global (16 KB,
// L1-hot) -> no LDS, no barriers, no bank conflicts. 8 independent 16B loads.
template<typename PT>
__global__ __launch_bounds__(256) void k_rows(const PT* __restrict__ P,
                                              const float* __restrict__ vinv,
                                              float* __restrict__ rsum) {
    const int row  = (blockIdx.x << 2) + (threadIdx.x >> 6);
    const int lane = threadIdx.x & 63;
    const PT* rp = P + (size_t)row * N;
    const float4* vv = (const float4*)vinv;
    float accA = 0.f, accB = 0.f;
    #pragma unroll
    for (int k = 0; k < 8; ++k) {
        const int e = (k * 64 + lane) * 8;
        V8 p = loadP8(rp, e);
        float4 v0 = vv[(e >> 2)];
        float4 v1 = vv[(e >> 2) + 1];
        accA += (p.v[0] * v0.x + p.v[1] * v0.y) + (p.v[2] * v0.z + p.v[3] * v0.w);
        accB += (p.v[4] * v1.x + p.v[5] * v1.y) + (p.v[6] * v1.z + p.v[7] * v1.w);
    }
    float s = accA + accB;
    #pragma unroll
    for (int off = 32; off; off >>= 1) s += __shfl_xor(s, off, 64);
    if (lane == 0) rsum[row] = s;
}

// ------------------------------------------------------------- col pass -----
// Grid (8,32): blockIdx.x = 512-col strip, blockIdx.y = 128-row chunk.
// Wave reads 1 KiB contiguous per row (perfect coalescing), 8-deep unroll.
// Per-wave partials -> atomicAdd. Ticket: last block computes vinv=rcp(csum)
// and re-zeros csum for the next iteration.
template<typename PT>
__global__ __launch_bounds__(256) void k_cols(const PT* __restrict__ P,
                                              const float* __restrict__ rsum,
                                              float* __restrict__ csum,
                                              float* __restrict__ vinv,
                                              int* __restrict__ counter,
                                              int nblocks) {
    const int wave = threadIdx.x >> 6;                 // 0..3
    const int lane = threadIdx.x & 63;
    const int col0 = blockIdx.x * 512 + lane * 8;
    const int row0 = blockIdx.y * 128 + wave * 32;
    float acc[8] = {0, 0, 0, 0, 0, 0, 0, 0};
    #pragma unroll 8
    for (int i = 0; i < 32; ++i) {
        const int r = row0 + i;
        const float ui = __builtin_amdgcn_rcpf(rsum[r]);
        V8 p = loadP8(P + (size_t)r * N, col0);
        #pragma unroll
        for (int k = 0; k < 8; ++k) acc[k] += p.v[k] * ui;
    }
    #pragma unroll
    for (int k = 0; k < 8; ++k) atomicAdd(&csum[col0 + k], acc[k]);

    __threadfence();
    __syncthreads();
    __shared__ int sticket;
    if (threadIdx.x == 0) sticket = atomicAdd(counter, 1);
    __syncthreads();
    if (sticket == nblocks - 1) {
        __threadfence();   // acquire: see all blocks' csum atomics
        for (int i = threadIdx.x; i < N; i += 256) {
            vinv[i] = __builtin_amdgcn_rcpf(csum[i]);
            csum[i] = 0.0f;
        }
        if (threadIdx.x == 0) *counter = 0;
    }
}

// --------------------------------------------------------------- final ------
template<typename PT>
__global__ __launch_bounds__(256) void k_final(const PT* __restrict__ P,
                                               const float* __restrict__ rsum,
                                               const float* __restrict__ vinv,
                                               float* __restrict__ out) {
    const int idx    = blockIdx.x * blockDim.x + threadIdx.x;
    const int total8 = N * N / 8;
    const int stride = gridDim.x * blockDim.x;
    const float4* vv = (const float4*)vinv;
    float4* o4 = (float4*)out;
    for (int v = idx; v < total8; v += stride) {
        const int row = v >> 9;                  // 512 ushort8 vectors per row
        const int e   = (v & 511) * 8;
        const float ui = __builtin_amdgcn_rcpf(rsum[row]);
        V8 p = loadP8(P + (size_t)row * N, e);
        float4 v0 = vv[(e >> 2)], v1 = vv[(e >> 2) + 1];
        float4 a, b;
        a.x = p.v[0] * ui * v0.x;  a.y = p.v[1] * ui * v0.y;
        a.z = p.v[2] * ui * v0.z;  a.w = p.v[3] * ui * v0.w;
        b.x = p.v[4] * ui * v1.x;  b.y = p.v[5] * ui * v1.y;
        b.z = p.v[6] * ui * v1.z;  b.w = p.v[7] * ui * v1.w;
        o4[2 * (size_t)v]     = a;
        o4[2 * (size_t)v + 1] = b;
    }
}

// ------------------------------------------------------------- launcher -----
extern "C" void kernel_launch(void* const* d_in, const int* in_sizes, int n_in,
                              void* d_out, int out_size, void* d_ws, size_t ws_size,
                              hipStream_t stream) {
    const float* eps  = (const float*)d_in[0];
    const float* mean = (const float*)d_in[1];
    const float* stdv = (const float*)d_in[2];
    float* out = (float*)d_out;
    char* ws = (char*)d_ws;

    const size_t pBytes  = (size_t)N * N * sizeof(unsigned short);  // 32 MiB
    const size_t vecVyts = (size_t)3 * N * sizeof(float) + 64;

    if (ws_size >= pBytes + vecVyts) {
        // bf16 P in workspace
        unsigned short* P = (unsigned short*)ws;
        float* rsum  = (float*)(ws + pBytes);
        float* csum  = rsum + N;
        float* vinv  = csum + N;
        int* counter = (int*)(vinv + N);
        k_init<unsigned short><<<2048, 256, 0, stream>>>(eps, mean, stdv, P, csum, vinv, counter);
        for (int t = 0; t < IT; ++t) {
            k_rows<unsigned short><<<1024, 256, 0, stream>>>(P, vinv, rsum);
            k_cols<unsigned short><<<dim3(8, 32), 256, 0, stream>>>(P, rsum, csum, vinv, counter, 256);
        }
        k_final<unsigned short><<<1024, 256, 0, stream>>>(P, rsum, vinv, out);
    } else {
        // fallback: f32 P lives in d_out; final pass rewrites it in place
        float* P = out;
        float* rsum  = (float*)ws;
        float* csum  = rsum + N;
        float* vinv  = csum + N;
        int* counter = (int*)(vinv + N);
        k_init<float><<<2048, 256, 0, stream>>>(eps, mean, stdv, P, csum, vinv, counter);
        for (int t = 0; t < IT; ++t) {
            k_rows<float><<<1024, 256, 0, stream>>>(P, vinv, rsum);
            k_cols<float><<<dim3(8, 32), 256, 0, stream>>>(P, rsum, csum, vinv, counter, 256);
        }
        k_final<float><<<1024, 256, 0, stream>>>(P, rsum, vinv, out);
    }
}